// Round 3
// baseline (930.583 us; speedup 1.0000x reference)
//
#include <hip/hip_runtime.h>
#include <cstdint>
#include <cstddef>

// Problem constants
#define T_TOK 8192
#define HDIM  1024
#define FDIM  2048
#define NEXP  16
#define CAP   1280

typedef __bf16 bf16x8 __attribute__((ext_vector_type(8)));
typedef float  f32x4  __attribute__((ext_vector_type(4)));

__device__ inline void gld16(const void* g, void* l) {
  __builtin_amdgcn_global_load_lds(
      (__attribute__((address_space(1))) void*)g,
      (__attribute__((address_space(3))) void*)l, 16, 0, 0);
}

// ---------------- Router: one wave per token ----------------
__global__ __launch_bounds__(256) void router_kernel(
    const float* __restrict__ x, const float* __restrict__ wr,
    int* __restrict__ eidx, float* __restrict__ eprob) {
  int t = blockIdx.x * 4 + (threadIdx.x >> 6);
  int lane = threadIdx.x & 63;
  float acc[NEXP];
#pragma unroll
  for (int e = 0; e < NEXP; ++e) acc[e] = 0.f;
  const float4* xp = (const float4*)(x + (size_t)t * HDIM + lane * 16);
#pragma unroll
  for (int q = 0; q < 4; ++q) {
    float4 xv = xp[q];
    float xa[4] = {xv.x, xv.y, xv.z, xv.w};
#pragma unroll
    for (int ii = 0; ii < 4; ++ii) {
      int h = lane * 16 + q * 4 + ii;
      const float4* wp = (const float4*)(wr + (size_t)h * NEXP);
      float w[NEXP];
      float4 w0 = wp[0], w1 = wp[1], w2 = wp[2], w3 = wp[3];
      w[0]=w0.x; w[1]=w0.y; w[2]=w0.z; w[3]=w0.w;
      w[4]=w1.x; w[5]=w1.y; w[6]=w1.z; w[7]=w1.w;
      w[8]=w2.x; w[9]=w2.y; w[10]=w2.z; w[11]=w2.w;
      w[12]=w3.x; w[13]=w3.y; w[14]=w3.z; w[15]=w3.w;
#pragma unroll
      for (int e = 0; e < NEXP; ++e) acc[e] += xa[ii] * w[e];
    }
  }
#pragma unroll
  for (int e = 0; e < NEXP; ++e) {
#pragma unroll
    for (int s = 32; s > 0; s >>= 1) acc[e] += __shfl_xor(acc[e], s);
  }
  if (lane == 0) {
    float l0 = -1e30f, l1 = -1e30f; int i0 = 0, i1 = 0;
#pragma unroll
    for (int e = 0; e < NEXP; ++e) {
      float v = acc[e];
      if (v > l0) { l1 = l0; i1 = i0; l0 = v; i0 = e; }
      else if (v > l1) { l1 = v; i1 = e; }
    }
    float p0 = 1.f / (1.f + __expf(l1 - l0));  // == softmax-then-renorm over top2
    eidx[t * 2 + 0] = i0; eidx[t * 2 + 1] = i1;
    eprob[t * 2 + 0] = p0; eprob[t * 2 + 1] = 1.f - p0;
  }
}

// ------------- Positions: single block, deterministic prefix count -------------
__global__ __launch_bounds__(256) void pos_kernel(
    const int* __restrict__ eidx, const float* __restrict__ eprob,
    int* __restrict__ slot_token, float* __restrict__ slot_prob) {
  __shared__ int scan[256][NEXP];
  int tid = threadIdx.x;
  int cnt[NEXP];
#pragma unroll
  for (int e = 0; e < NEXP; ++e) cnt[e] = 0;
  int base_i = tid * 64;
  const int4* ep = (const int4*)(eidx + base_i);
  for (int i = 0; i < 16; ++i) {
    int4 v = ep[i];
    cnt[v.x]++; cnt[v.y]++; cnt[v.z]++; cnt[v.w]++;
  }
#pragma unroll
  for (int e = 0; e < NEXP; ++e) scan[tid][e] = cnt[e];
  __syncthreads();
  if (tid < NEXP) {
    int run = 0;
    for (int i = 0; i < 256; ++i) { int v = scan[i][tid]; scan[i][tid] = run; run += v; }
  }
  __syncthreads();
  int basec[NEXP];
#pragma unroll
  for (int e = 0; e < NEXP; ++e) basec[e] = scan[tid][e];
  for (int i = 0; i < 64; ++i) {
    int fi = base_i + i;
    int e = eidx[fi];
    int p = basec[e]++;
    if (p < CAP) {
      slot_token[e * CAP + p] = fi >> 1;   // token id
      slot_prob[e * CAP + p] = eprob[fi];
    }
  }
}

// ------------- Scatter x rows into bf16 dispatch buffer (zeros for empty) -------------
__global__ __launch_bounds__(256) void scatter_kernel(
    const float* __restrict__ x, const int* __restrict__ slot_token,
    __bf16* __restrict__ disp) {
  int s = blockIdx.x * 4 + (threadIdx.x >> 6);
  int lane = threadIdx.x & 63;
  int tok = slot_token[s];
  __bf16 vals[16] __attribute__((aligned(16)));
  if (tok >= 0) {
    const float4* xp = (const float4*)(x + (size_t)tok * HDIM + lane * 16);
#pragma unroll
    for (int q = 0; q < 4; ++q) {
      float4 v = xp[q];
      vals[q * 4 + 0] = (__bf16)v.x; vals[q * 4 + 1] = (__bf16)v.y;
      vals[q * 4 + 2] = (__bf16)v.z; vals[q * 4 + 3] = (__bf16)v.w;
    }
  } else {
#pragma unroll
    for (int q = 0; q < 16; ++q) vals[q] = (__bf16)0.f;
  }
  uint4* dst = (uint4*)(disp + (size_t)s * HDIM + lane * 16);
  dst[0] = ((uint4*)vals)[0];
  dst[1] = ((uint4*)vals)[1];
}

// ------------- Transpose + fp32->bf16 cast: (R,Cc) -> (Cc,R), per expert -------------
__global__ __launch_bounds__(256) void transpose_cast_kernel(
    const float* __restrict__ src, __bf16* __restrict__ dst, int R, int Cc) {
  int e = blockIdx.z;
  src += (size_t)e * R * Cc;
  dst += (size_t)e * R * Cc;
  __shared__ float tile[64][65];
  int gy = blockIdx.y * 64;  // src row base
  int gx = blockIdx.x * 64;  // src col base
  int tid = threadIdx.x;
  int r = tid >> 4;
  int c4 = (tid & 15) * 4;
#pragma unroll
  for (int rr = 0; rr < 4; ++rr) {
    float4 v = *(const float4*)(src + (size_t)(gy + r + rr * 16) * Cc + gx + c4);
    tile[r + rr * 16][c4 + 0] = v.x;
    tile[r + rr * 16][c4 + 1] = v.y;
    tile[r + rr * 16][c4 + 2] = v.z;
    tile[r + rr * 16][c4 + 3] = v.w;
  }
  __syncthreads();
  int r2 = tid >> 2;          // out row (= src col) 0..63
  int cb = (tid & 3) * 16;    // out col chunk
  __bf16 o[16] __attribute__((aligned(16)));
#pragma unroll
  for (int i = 0; i < 16; ++i) o[i] = (__bf16)tile[cb + i][r2];
  uint4* dp = (uint4*)(dst + (size_t)(gx + r2) * R + gy + cb);
  dp[0] = ((uint4*)o)[0];
  dp[1] = ((uint4*)o)[1];
}

// ------------- MFMA GEMM: 128x128 tile, BK=32, double-buffered, 32KB LDS -------------
// A: (M,K) row-major bf16, Bt: (N,K) row-major bf16, per-expert contiguous.
// BK=32 -> 16KB per buffer (A 8KB + B 8KB), 2 buffers = 32KB -> 5 blocks/CU
// (VGPR 88 <= 102). The double-buffer keeps 4 loads in flight across each
// compute phase; 5-way block TLP covers the residual latency.
// LDS rows are 64B (32 bf16): swizzle 16B-chunk index with (row>>1)&3, applied
// in the global source address (LDS dst must stay linear for global_load_lds)
// and in the fragment reads -> only free 2-way bank aliasing remains.
template <int EPI>
__global__ __launch_bounds__(256, 5) void moe_gemm_kernel(
    const __bf16* __restrict__ A, const __bf16* __restrict__ Bt,
    const float* __restrict__ bias, __bf16* __restrict__ Hout,
    const int* __restrict__ slot_token, const float* __restrict__ slot_prob,
    float* __restrict__ out, int M, int N, int Kd) {
  const int e = blockIdx.z;
  const int m0 = blockIdx.y * 128, n0 = blockIdx.x * 128;
  const __bf16* Ae = A + (size_t)e * M * Kd;
  const __bf16* Be = Bt + (size_t)e * N * Kd;
  __shared__ __bf16 lds[2 * 8192];  // 2 buffers x (A 4096 + B 4096 elems) = 32KB
  const int tid = threadIdx.x, wave = tid >> 6, lane = tid & 63;
  const int quad = lane >> 4, l15 = lane & 15;
  const int wm = (wave >> 1) * 64, wn = (wave & 1) * 64;
  f32x4 acc[4][4] = {};
  const int Kb = Kd * 2;  // row bytes
  const int ktiles = Kd >> 5;

  // Per-lane staging geometry (constant across iterations). Tile row = 64B.
  const int bofs0 = wave * 2048;                 // wave-uniform byte base in tile
  int srow[2], sgcol[2];
#pragma unroll
  for (int rr = 0; rr < 2; ++rr) {
    int lofs = bofs0 + rr * 1024 + lane * 16;
    int row = lofs >> 6;                         // 64B per tile row (32 bf16)
    int chunk = (lofs >> 4) & 3;                 // 16B chunk within row
    srow[rr] = row;
    sgcol[rr] = (chunk ^ ((row >> 1) & 3)) * 16; // swizzled source col (bytes)
  }

  auto stage = [&](int kt, int b) {
    char* dstA = (char*)lds + b * 16384;
    char* dstB = dstA + 8192;
#pragma unroll
    for (int rr = 0; rr < 2; ++rr) {
      int bofs = bofs0 + rr * 1024;
      gld16((const char*)Ae + (size_t)(m0 + srow[rr]) * Kb + kt * 64 + sgcol[rr],
            dstA + bofs);
      gld16((const char*)Be + (size_t)(n0 + srow[rr]) * Kb + kt * 64 + sgcol[rr],
            dstB + bofs);
    }
  };

  stage(0, 0);
  for (int kt = 0; kt < ktiles; ++kt) {
    const int b = kt & 1;
    __builtin_amdgcn_s_waitcnt(0x0f70);   // vmcnt(0): my loads for buf b done
    __builtin_amdgcn_s_barrier();         // everyone's loads done; prev reads done
    if (kt + 1 < ktiles) stage(kt + 1, b ^ 1);
    const __bf16* La = lds + b * 8192;
    const __bf16* Lb = La + 4096;
    bf16x8 av[4], bv[4];
#pragma unroll
    for (int i = 0; i < 4; ++i) {
      int r = wm + i * 16 + l15;
      av[i] = *(const bf16x8*)&La[r * 32 + ((quad ^ ((r >> 1) & 3)) << 3)];
    }
#pragma unroll
    for (int j = 0; j < 4; ++j) {
      int r = wn + j * 16 + l15;
      bv[j] = *(const bf16x8*)&Lb[r * 32 + ((quad ^ ((r >> 1) & 3)) << 3)];
    }
#pragma unroll
    for (int i = 0; i < 4; ++i)
#pragma unroll
      for (int j = 0; j < 4; ++j)
        acc[i][j] = __builtin_amdgcn_mfma_f32_16x16x32_bf16(av[i], bv[j], acc[i][j], 0, 0, 0);
  }
  // Epilogue. C/D layout: col = lane&15, row = quad*4 + reg  [verified m89/m91]
  if (EPI == 1) {
    __bf16* He = Hout + (size_t)e * M * N;
#pragma unroll
    for (int i = 0; i < 4; ++i) {
#pragma unroll
      for (int r = 0; r < 4; ++r) {
        int m = m0 + wm + i * 16 + quad * 4 + r;
#pragma unroll
        for (int j = 0; j < 4; ++j) {
          int n = n0 + wn + j * 16 + l15;
          float v = acc[i][j][r] + bias[(size_t)e * N + n];
          // tanh-approx GELU (JAX default approximate=True)
          float u = 0.7978845608028654f * (v + 0.044715f * v * v * v);
          float ex = __expf(-2.f * fabsf(u));
          float th = (1.f - ex) / (1.f + ex);
          th = copysignf(th, u);
          He[(size_t)m * N + n] = (__bf16)(0.5f * v * (1.f + th));
        }
      }
    }
  } else {
    const int* st = slot_token + e * CAP;
    const float* sp = slot_prob + e * CAP;
#pragma unroll
    for (int i = 0; i < 4; ++i) {
#pragma unroll
      for (int r = 0; r < 4; ++r) {
        int m = m0 + wm + i * 16 + quad * 4 + r;
        int tok = st[m];
        if (tok >= 0) {
          float p = sp[m];
#pragma unroll
          for (int j = 0; j < 4; ++j) {
            int n = n0 + wn + j * 16 + l15;
            float v = acc[i][j][r] + bias[(size_t)e * N + n];
            atomicAdd(out + (size_t)tok * HDIM + n, p * v);
          }
        }
      }
    }
  }
}

extern "C" void kernel_launch(void* const* d_in, const int* in_sizes, int n_in,
                              void* d_out, int out_size, void* d_ws, size_t ws_size,
                              hipStream_t stream) {
  const float* x  = (const float*)d_in[0];
  const float* wr = (const float*)d_in[1];
  const float* w1 = (const float*)d_in[2];
  const float* b1 = (const float*)d_in[3];
  const float* w2 = (const float*)d_in[4];
  const float* b2 = (const float*)d_in[5];
  float* out = (float*)d_out;

  // Workspace layout (bytes)
  char* ws = (char*)d_ws;
  size_t off = 0;
  __bf16* w1t = (__bf16*)(ws + off); off += (size_t)NEXP * FDIM * HDIM * 2;   // 64MB (E,F,H)
  __bf16* w2t = (__bf16*)(ws + off); off += (size_t)NEXP * HDIM * FDIM * 2;   // 64MB (E,H,F)
  __bf16* disp = (__bf16*)(ws + off); off += (size_t)NEXP * CAP * HDIM * 2;   // 40MB (E*C,H)
  __bf16* hbuf = (__bf16*)(ws + off); off += (size_t)NEXP * CAP * FDIM * 2;   // 80MB (E*C,F)
  int*   slot_token = (int*)(ws + off);  off += (size_t)NEXP * CAP * 4;
  float* slot_prob  = (float*)(ws + off); off += (size_t)NEXP * CAP * 4;
  int*   eidx  = (int*)(ws + off);  off += (size_t)T_TOK * 2 * 4;
  float* eprob = (float*)(ws + off); off += (size_t)T_TOK * 2 * 4;
  if (ws_size < off) return;  // insufficient scratch

  // Init: empty slots = -1, output accumulates via atomics
  hipMemsetAsync(slot_token, 0xFF, (size_t)NEXP * CAP * 4, stream);
  hipMemsetAsync(d_out, 0, (size_t)T_TOK * HDIM * 4, stream);

  // Weight transpose+cast: w1 (E,H,F)->(E,F,H), w2 (E,F,H)->(E,H,F)
  transpose_cast_kernel<<<dim3(FDIM / 64, HDIM / 64, NEXP), 256, 0, stream>>>(w1, w1t, HDIM, FDIM);
  transpose_cast_kernel<<<dim3(HDIM / 64, FDIM / 64, NEXP), 256, 0, stream>>>(w2, w2t, FDIM, HDIM);

  // Routing
  router_kernel<<<T_TOK / 4, 256, 0, stream>>>(x, wr, eidx, eprob);
  pos_kernel<<<1, 256, 0, stream>>>(eidx, eprob, slot_token, slot_prob);
  scatter_kernel<<<NEXP * CAP / 4, 256, 0, stream>>>(x, slot_token, disp);

  // Expert FFN
  moe_gemm_kernel<1><<<dim3(FDIM / 128, CAP / 128, NEXP), 256, 0, stream>>>(
      disp, w1t, b1, hbuf, nullptr, nullptr, nullptr, CAP, FDIM, HDIM);
  moe_gemm_kernel<2><<<dim3(HDIM / 128, CAP / 128, NEXP), 256, 0, stream>>>(
      hbuf, w2t, b2, nullptr, slot_token, slot_prob, out, CAP, HDIM, FDIM);
}

// Round 4
// 778.465 us; speedup vs baseline: 1.1954x; 1.1954x over previous
//
#include <hip/hip_runtime.h>
#include <cstdint>
#include <cstddef>

// Problem constants
#define T_TOK 8192
#define HDIM  1024
#define FDIM  2048
#define NEXP  16
#define CAP   1280

typedef __bf16 bf16x8 __attribute__((ext_vector_type(8)));
typedef float  f32x4  __attribute__((ext_vector_type(4)));

__device__ inline void gld16(const void* g, void* l) {
  __builtin_amdgcn_global_load_lds(
      (__attribute__((address_space(1))) void*)g,
      (__attribute__((address_space(3))) void*)l, 16, 0, 0);
}

// ---------------- Router: one wave per token ----------------
__global__ __launch_bounds__(256) void router_kernel(
    const float* __restrict__ x, const float* __restrict__ wr,
    int* __restrict__ eidx, float* __restrict__ eprob) {
  int t = blockIdx.x * 4 + (threadIdx.x >> 6);
  int lane = threadIdx.x & 63;
  float acc[NEXP];
#pragma unroll
  for (int e = 0; e < NEXP; ++e) acc[e] = 0.f;
  const float4* xp = (const float4*)(x + (size_t)t * HDIM + lane * 16);
#pragma unroll
  for (int q = 0; q < 4; ++q) {
    float4 xv = xp[q];
    float xa[4] = {xv.x, xv.y, xv.z, xv.w};
#pragma unroll
    for (int ii = 0; ii < 4; ++ii) {
      int h = lane * 16 + q * 4 + ii;
      const float4* wp = (const float4*)(wr + (size_t)h * NEXP);
      float w[NEXP];
      float4 w0 = wp[0], w1 = wp[1], w2 = wp[2], w3 = wp[3];
      w[0]=w0.x; w[1]=w0.y; w[2]=w0.z; w[3]=w0.w;
      w[4]=w1.x; w[5]=w1.y; w[6]=w1.z; w[7]=w1.w;
      w[8]=w2.x; w[9]=w2.y; w[10]=w2.z; w[11]=w2.w;
      w[12]=w3.x; w[13]=w3.y; w[14]=w3.z; w[15]=w3.w;
#pragma unroll
      for (int e = 0; e < NEXP; ++e) acc[e] += xa[ii] * w[e];
    }
  }
#pragma unroll
  for (int e = 0; e < NEXP; ++e) {
#pragma unroll
    for (int s = 32; s > 0; s >>= 1) acc[e] += __shfl_xor(acc[e], s);
  }
  if (lane == 0) {
    float l0 = -1e30f, l1 = -1e30f; int i0 = 0, i1 = 0;
#pragma unroll
    for (int e = 0; e < NEXP; ++e) {
      float v = acc[e];
      if (v > l0) { l1 = l0; i1 = i0; l0 = v; i0 = e; }
      else if (v > l1) { l1 = v; i1 = e; }
    }
    float p0 = 1.f / (1.f + __expf(l1 - l0));  // == softmax-then-renorm over top2
    eidx[t * 2 + 0] = i0; eidx[t * 2 + 1] = i1;
    eprob[t * 2 + 0] = p0; eprob[t * 2 + 1] = 1.f - p0;
  }
}

// ------------- Positions: single block, deterministic prefix count -------------
__global__ __launch_bounds__(256) void pos_kernel(
    const int* __restrict__ eidx, const float* __restrict__ eprob,
    int* __restrict__ slot_token, float* __restrict__ slot_prob) {
  __shared__ int scan[256][NEXP];
  int tid = threadIdx.x;
  int cnt[NEXP];
#pragma unroll
  for (int e = 0; e < NEXP; ++e) cnt[e] = 0;
  int base_i = tid * 64;
  const int4* ep = (const int4*)(eidx + base_i);
  for (int i = 0; i < 16; ++i) {
    int4 v = ep[i];
    cnt[v.x]++; cnt[v.y]++; cnt[v.z]++; cnt[v.w]++;
  }
#pragma unroll
  for (int e = 0; e < NEXP; ++e) scan[tid][e] = cnt[e];
  __syncthreads();
  if (tid < NEXP) {
    int run = 0;
    for (int i = 0; i < 256; ++i) { int v = scan[i][tid]; scan[i][tid] = run; run += v; }
  }
  __syncthreads();
  int basec[NEXP];
#pragma unroll
  for (int e = 0; e < NEXP; ++e) basec[e] = scan[tid][e];
  for (int i = 0; i < 64; ++i) {
    int fi = base_i + i;
    int e = eidx[fi];
    int p = basec[e]++;
    if (p < CAP) {
      slot_token[e * CAP + p] = fi >> 1;   // token id
      slot_prob[e * CAP + p] = eprob[fi];
    }
  }
}

// ------------- Scatter x rows into bf16 dispatch buffer (zeros for empty) -------------
__global__ __launch_bounds__(256) void scatter_kernel(
    const float* __restrict__ x, const int* __restrict__ slot_token,
    __bf16* __restrict__ disp) {
  int s = blockIdx.x * 4 + (threadIdx.x >> 6);
  int lane = threadIdx.x & 63;
  int tok = slot_token[s];
  __bf16 vals[16] __attribute__((aligned(16)));
  if (tok >= 0) {
    const float4* xp = (const float4*)(x + (size_t)tok * HDIM + lane * 16);
#pragma unroll
    for (int q = 0; q < 4; ++q) {
      float4 v = xp[q];
      vals[q * 4 + 0] = (__bf16)v.x; vals[q * 4 + 1] = (__bf16)v.y;
      vals[q * 4 + 2] = (__bf16)v.z; vals[q * 4 + 3] = (__bf16)v.w;
    }
  } else {
#pragma unroll
    for (int q = 0; q < 16; ++q) vals[q] = (__bf16)0.f;
  }
  uint4* dst = (uint4*)(disp + (size_t)s * HDIM + lane * 16);
  dst[0] = ((uint4*)vals)[0];
  dst[1] = ((uint4*)vals)[1];
}

// ------------- Transpose + fp32->bf16 cast: (R,Cc) -> (Cc,R), per expert -------------
__global__ __launch_bounds__(256) void transpose_cast_kernel(
    const float* __restrict__ src, __bf16* __restrict__ dst, int R, int Cc) {
  int e = blockIdx.z;
  src += (size_t)e * R * Cc;
  dst += (size_t)e * R * Cc;
  __shared__ float tile[64][65];
  int gy = blockIdx.y * 64;  // src row base
  int gx = blockIdx.x * 64;  // src col base
  int tid = threadIdx.x;
  int r = tid >> 4;
  int c4 = (tid & 15) * 4;
#pragma unroll
  for (int rr = 0; rr < 4; ++rr) {
    float4 v = *(const float4*)(src + (size_t)(gy + r + rr * 16) * Cc + gx + c4);
    tile[r + rr * 16][c4 + 0] = v.x;
    tile[r + rr * 16][c4 + 1] = v.y;
    tile[r + rr * 16][c4 + 2] = v.z;
    tile[r + rr * 16][c4 + 3] = v.w;
  }
  __syncthreads();
  int r2 = tid >> 2;          // out row (= src col) 0..63
  int cb = (tid & 3) * 16;    // out col chunk
  __bf16 o[16] __attribute__((aligned(16)));
#pragma unroll
  for (int i = 0; i < 16; ++i) o[i] = (__bf16)tile[cb + i][r2];
  uint4* dp = (uint4*)(dst + (size_t)(gx + r2) * R + gy + cb);
  dp[0] = ((uint4*)o)[0];
  dp[1] = ((uint4*)o)[1];
}

// ------------- MFMA GEMM: 128x128 tile, BK=32, TRIPLE-buffered, 48KB LDS -------------
// A: (M,K) row-major bf16, Bt: (N,K) row-major bf16, per-expert contiguous.
// 3 buffers x 16KB = 48KB -> 3 blocks/CU; __launch_bounds__(256,3) caps VGPR
// at ~170 (kernel needs ~150 incl. AGPR acc -> NO spills; round-3's (256,5)
// cap at ~102 spilled: WRITE_SIZE 65->212MB).
// Prefetch depth 2: at iter kt we wait vmcnt(4) -> retires only stage(kt)
// (issued 2 compute phases ago); stage(kt+1)'s 4 loads stay in flight across
// the barrier (AITER-style "never vmcnt(0) in steady state").
// LDS rows are 64B: swizzle 16B-chunk with (row>>1)&3 in the global source
// address and fragment reads (bank conflicts measured 0 in r3).
template <int EPI>
__global__ __launch_bounds__(256, 3) void moe_gemm_kernel(
    const __bf16* __restrict__ A, const __bf16* __restrict__ Bt,
    const float* __restrict__ bias, __bf16* __restrict__ Hout,
    const int* __restrict__ slot_token, const float* __restrict__ slot_prob,
    float* __restrict__ out, int M, int N, int Kd) {
  const int e = blockIdx.z;
  const int m0 = blockIdx.y * 128, n0 = blockIdx.x * 128;
  const __bf16* Ae = A + (size_t)e * M * Kd;
  const __bf16* Be = Bt + (size_t)e * N * Kd;
  __shared__ __bf16 lds[3 * 8192];  // 3 buffers x (A 4096 + B 4096 elems) = 48KB
  const int tid = threadIdx.x, wave = tid >> 6, lane = tid & 63;
  const int quad = lane >> 4, l15 = lane & 15;
  const int wm = (wave >> 1) * 64, wn = (wave & 1) * 64;
  f32x4 acc[4][4] = {};
  const int Kb = Kd * 2;  // row bytes
  const int ktiles = Kd >> 5;

  // Per-lane staging geometry (constant across iterations). Tile row = 64B.
  const int bofs0 = wave * 2048;                 // wave-uniform byte base in tile
  int srow[2], sgcol[2];
#pragma unroll
  for (int rr = 0; rr < 2; ++rr) {
    int lofs = bofs0 + rr * 1024 + lane * 16;
    int row = lofs >> 6;                         // 64B per tile row (32 bf16)
    int chunk = (lofs >> 4) & 3;                 // 16B chunk within row
    srow[rr] = row;
    sgcol[rr] = (chunk ^ ((row >> 1) & 3)) * 16; // swizzled source col (bytes)
  }

  auto stage = [&](int kt, int b) {
    char* dstA = (char*)lds + b * 16384;
    char* dstB = dstA + 8192;
#pragma unroll
    for (int rr = 0; rr < 2; ++rr) {
      int bofs = bofs0 + rr * 1024;
      gld16((const char*)Ae + (size_t)(m0 + srow[rr]) * Kb + kt * 64 + sgcol[rr],
            dstA + bofs);
      gld16((const char*)Be + (size_t)(n0 + srow[rr]) * Kb + kt * 64 + sgcol[rr],
            dstB + bofs);
    }
  };

  stage(0, 0);
  stage(1, 1);
  int bcur = 0, bstage = 2;   // buf for compute at kt; buf for stage(kt+2)
  for (int kt = 0; kt < ktiles; ++kt) {
    if (kt + 1 < ktiles) __builtin_amdgcn_s_waitcnt(0x0f74);  // vmcnt(4): stage(kt) done
    else                 __builtin_amdgcn_s_waitcnt(0x0f70);  // vmcnt(0): last tile
    __builtin_amdgcn_s_barrier();
    if (kt + 2 < ktiles) stage(kt + 2, bstage);
    const __bf16* La = lds + bcur * 8192;
    const __bf16* Lb = La + 4096;
    bf16x8 av[4], bv[4];
#pragma unroll
    for (int i = 0; i < 4; ++i) {
      int r = wm + i * 16 + l15;
      av[i] = *(const bf16x8*)&La[r * 32 + ((quad ^ ((r >> 1) & 3)) << 3)];
    }
#pragma unroll
    for (int j = 0; j < 4; ++j) {
      int r = wn + j * 16 + l15;
      bv[j] = *(const bf16x8*)&Lb[r * 32 + ((quad ^ ((r >> 1) & 3)) << 3)];
    }
#pragma unroll
    for (int i = 0; i < 4; ++i)
#pragma unroll
      for (int j = 0; j < 4; ++j)
        acc[i][j] = __builtin_amdgcn_mfma_f32_16x16x32_bf16(av[i], bv[j], acc[i][j], 0, 0, 0);
    bcur = (bcur == 2) ? 0 : bcur + 1;
    bstage = (bstage == 2) ? 0 : bstage + 1;
  }
  // Epilogue. C/D layout: col = lane&15, row = quad*4 + reg  [verified m89/m91]
  if (EPI == 1) {
    __bf16* He = Hout + (size_t)e * M * N;
#pragma unroll
    for (int i = 0; i < 4; ++i) {
#pragma unroll
      for (int r = 0; r < 4; ++r) {
        int m = m0 + wm + i * 16 + quad * 4 + r;
#pragma unroll
        for (int j = 0; j < 4; ++j) {
          int n = n0 + wn + j * 16 + l15;
          float v = acc[i][j][r] + bias[(size_t)e * N + n];
          // tanh-approx GELU (JAX default approximate=True)
          float u = 0.7978845608028654f * (v + 0.044715f * v * v * v);
          float ex = __expf(-2.f * fabsf(u));
          float th = (1.f - ex) / (1.f + ex);
          th = copysignf(th, u);
          He[(size_t)m * N + n] = (__bf16)(0.5f * v * (1.f + th));
        }
      }
    }
  } else {
    const int* st = slot_token + e * CAP;
    const float* sp = slot_prob + e * CAP;
#pragma unroll
    for (int i = 0; i < 4; ++i) {
#pragma unroll
      for (int r = 0; r < 4; ++r) {
        int m = m0 + wm + i * 16 + quad * 4 + r;
        int tok = st[m];
        if (tok >= 0) {
          float p = sp[m];
#pragma unroll
          for (int j = 0; j < 4; ++j) {
            int n = n0 + wn + j * 16 + l15;
            float v = acc[i][j][r] + bias[(size_t)e * N + n];
            atomicAdd(out + (size_t)tok * HDIM + n, p * v);
          }
        }
      }
    }
  }
}

extern "C" void kernel_launch(void* const* d_in, const int* in_sizes, int n_in,
                              void* d_out, int out_size, void* d_ws, size_t ws_size,
                              hipStream_t stream) {
  const float* x  = (const float*)d_in[0];
  const float* wr = (const float*)d_in[1];
  const float* w1 = (const float*)d_in[2];
  const float* b1 = (const float*)d_in[3];
  const float* w2 = (const float*)d_in[4];
  const float* b2 = (const float*)d_in[5];
  float* out = (float*)d_out;

  // Workspace layout (bytes)
  char* ws = (char*)d_ws;
  size_t off = 0;
  __bf16* w1t = (__bf16*)(ws + off); off += (size_t)NEXP * FDIM * HDIM * 2;   // 64MB (E,F,H)
  __bf16* w2t = (__bf16*)(ws + off); off += (size_t)NEXP * HDIM * FDIM * 2;   // 64MB (E,H,F)
  __bf16* disp = (__bf16*)(ws + off); off += (size_t)NEXP * CAP * HDIM * 2;   // 40MB (E*C,H)
  __bf16* hbuf = (__bf16*)(ws + off); off += (size_t)NEXP * CAP * FDIM * 2;   // 80MB (E*C,F)
  int*   slot_token = (int*)(ws + off);  off += (size_t)NEXP * CAP * 4;
  float* slot_prob  = (float*)(ws + off); off += (size_t)NEXP * CAP * 4;
  int*   eidx  = (int*)(ws + off);  off += (size_t)T_TOK * 2 * 4;
  float* eprob = (float*)(ws + off); off += (size_t)T_TOK * 2 * 4;
  if (ws_size < off) return;  // insufficient scratch

  // Init: empty slots = -1, output accumulates via atomics
  hipMemsetAsync(slot_token, 0xFF, (size_t)NEXP * CAP * 4, stream);
  hipMemsetAsync(d_out, 0, (size_t)T_TOK * HDIM * 4, stream);

  // Weight transpose+cast: w1 (E,H,F)->(E,F,H), w2 (E,F,H)->(E,H,F)
  transpose_cast_kernel<<<dim3(FDIM / 64, HDIM / 64, NEXP), 256, 0, stream>>>(w1, w1t, HDIM, FDIM);
  transpose_cast_kernel<<<dim3(HDIM / 64, FDIM / 64, NEXP), 256, 0, stream>>>(w2, w2t, FDIM, HDIM);

  // Routing
  router_kernel<<<T_TOK / 4, 256, 0, stream>>>(x, wr, eidx, eprob);
  pos_kernel<<<1, 256, 0, stream>>>(eidx, eprob, slot_token, slot_prob);
  scatter_kernel<<<NEXP * CAP / 4, 256, 0, stream>>>(x, slot_token, disp);

  // Expert FFN
  moe_gemm_kernel<1><<<dim3(FDIM / 128, CAP / 128, NEXP), 256, 0, stream>>>(
      disp, w1t, b1, hbuf, nullptr, nullptr, nullptr, CAP, FDIM, HDIM);
  moe_gemm_kernel<2><<<dim3(HDIM / 128, CAP / 128, NEXP), 256, 0, stream>>>(
      hbuf, w2t, b2, nullptr, slot_token, slot_prob, out, CAP, HDIM, FDIM);
}